// Round 10
// baseline (198.622 us; speedup 1.0000x reference)
//
#include <hip/hip_runtime.h>
#include <hip/hip_bf16.h>

#define BB 8
#define SS 4096
#define DD 128
#define HH 8
#define NBUCK 64
#define CHUNKSZ 64
#define NCHUNK 512      // HH*SS/CHUNKSZ
#define HSTOT 32768     // HH*SS
#define ROWB 272        // bf16 tile row stride in bytes (128*2 + 16 pad)

typedef __attribute__((ext_vector_type(8))) short short8_t;   // 8 bf16 = 4 VGPR
typedef __attribute__((ext_vector_type(4))) float f32x4;
typedef __attribute__((ext_vector_type(4))) unsigned int u32x4;

static __device__ __forceinline__ unsigned short f2bf(float f) {
    __hip_bfloat16 h = __float2bfloat16(f);
    return *reinterpret_cast<unsigned short*>(&h);
}
static __device__ __forceinline__ unsigned int pk2bf(float lo, float hi) {
    __hip_bfloat162 h = __float22bfloat162_rn(make_float2(lo, hi));   // v_cvt_pk_bf16_f32
    return *reinterpret_cast<unsigned int*>(&h);
}
static __device__ __forceinline__ float bf2f(unsigned short u) {
    return __uint_as_float(((unsigned int)u) << 16);
}

// ---------------- Kernel A0: rot -> rotT (bf16, [col][f]) --------------------
__global__ __launch_bounds__(256) void rot_transpose_kernel(
    const float* __restrict__ rot, unsigned short* __restrict__ rotT)
{
    const int col = threadIdx.x;           // 0..255
    for (int f0 = 0; f0 < DD; f0 += 8) {
        float v[8];
        #pragma unroll
        for (int i = 0; i < 8; ++i) v[i] = rot[(size_t)(f0 + i) * 256 + col];
        uint4 pk;
        pk.x = pk2bf(v[0], v[1]); pk.y = pk2bf(v[2], v[3]);
        pk.z = pk2bf(v[4], v[5]); pk.w = pk2bf(v[6], v[7]);
        *reinterpret_cast<uint4*>(rotT + (size_t)col * DD + f0) = pk;
    }
}

// exact f64 dot for near-tie resolution (one code copy; cold path)
__device__ __noinline__ double f64dot_col(const float* __restrict__ qrow,
                                          const float* __restrict__ rot, int col)
{
    double a = 0.0;
    for (int f = 0; f < DD; ++f)
        a = fma((double)qrow[f], (double)rot[(size_t)f * 256 + col], a);
    return a;
}

// ---------------- Kernel A: LSH hashing via bf16 MFMA ------------------------
// D[col][tok] = rotT x qk^T per 16x16x32 tiles. Wave = 16 tokens x 256 cols,
// LDS-free. C layout: lane(cc,g) holds token cc, cols 16m+4g+r. Near-ties
// (top-2 gap < TAU=0.25 > 2x the max bf16-rounding error ~0.10) resolved by
// f64 recompute of flagged candidates (first-occurrence semantics).
__global__ __launch_bounds__(256) void hash_kernel(
    const float* __restrict__ qk, const float* __restrict__ rot,
    const unsigned short* __restrict__ rotT,
    unsigned char* __restrict__ bucket_ws, float* __restrict__ bucket_out)
{
    const int tid = threadIdx.x;
    const int bid = blockIdx.x;            // 0..511 = b(3) | tile(6)
    const int b   = bid >> 6;
    const int t0  = (bid & 63) * 64;
    const int w   = tid >> 6;              // wave: tokens t0+16w .. +15
    const int ln  = tid & 63;
    const int cc  = ln & 15;               // token lane
    const int g   = ln >> 4;               // k-slice / col-subrow group
    const int tglob = t0 + w * 16 + cc;

    const float* qrow = qk + ((size_t)b * SS + tglob) * DD;

    f32x4 acc[16];
    #pragma unroll
    for (int m = 0; m < 16; ++m) acc[m] = (f32x4){0.f, 0.f, 0.f, 0.f};

    #pragma unroll
    for (int ks = 0; ks < 4; ++ks) {
        // B operand: q[tok=cc][k = ks*32 + g*8 + e]
        float4 q0 = *reinterpret_cast<const float4*>(qrow + ks * 32 + g * 8);
        float4 q1 = *reinterpret_cast<const float4*>(qrow + ks * 32 + g * 8 + 4);
        u32x4 bq;
        bq.x = pk2bf(q0.x, q0.y); bq.y = pk2bf(q0.z, q0.w);
        bq.z = pk2bf(q1.x, q1.y); bq.w = pk2bf(q1.z, q1.w);
        short8_t bfr = __builtin_bit_cast(short8_t, bq);
        #pragma unroll
        for (int m = 0; m < 16; ++m) {
            short8_t af = *reinterpret_cast<const short8_t*>(
                rotT + (size_t)(16 * m + cc) * DD + ks * 32 + g * 8);
            acc[m] = __builtin_amdgcn_mfma_f32_16x16x32_bf16(af, bfr, acc[m], 0, 0, 0);
        }
    }

    const float TAU = 0.25f;
    #pragma unroll
    for (int h = 0; h < 8; ++h) {
        // local argmax over this lane's 16 candidates (8 cols x +/-), asc. idx
        float bv = -3.0e38f; int bi = 0;
        #pragma unroll
        for (int mi = 0; mi < 2; ++mi)
            #pragma unroll
            for (int r = 0; r < 4; ++r) {
                float v = acc[2 * h + mi][r];
                int   j = mi * 16 + 4 * g + r;
                if (v > bv) { bv = v; bi = j; }
            }
        #pragma unroll
        for (int mi = 0; mi < 2; ++mi)
            #pragma unroll
            for (int r = 0; r < 4; ++r) {
                float v = -acc[2 * h + mi][r];
                int   j = 32 + mi * 16 + 4 * g + r;
                if (v > bv) { bv = v; bi = j; }
            }
        // reduce across the 4 g-lanes of this token (lane ^16, ^32: same cc)
        #pragma unroll
        for (int off = 16; off < 64; off <<= 1) {
            float ov = __shfl_xor(bv, off);
            int   oi = __shfl_xor(bi, off);
            if (ov > bv || (ov == bv && oi < bi)) { bv = ov; bi = oi; }
        }
        const float thrv = bv - TAU;
        int cnt = 0;
        #pragma unroll
        for (int mi = 0; mi < 2; ++mi)
            #pragma unroll
            for (int r = 0; r < 4; ++r) {
                cnt += (acc[2 * h + mi][r]  > thrv) ? 1 : 0;
                cnt += (-acc[2 * h + mi][r] > thrv) ? 1 : 0;
            }
        #pragma unroll
        for (int off = 16; off < 64; off <<= 1) cnt += __shfl_xor(cnt, off);

        if (cnt > 1) {
            // rare exact path: f64 on flagged candidates only (bit-mask walk)
            unsigned int mask = 0;
            #pragma unroll
            for (int mi = 0; mi < 2; ++mi)
                #pragma unroll
                for (int r = 0; r < 4; ++r) {
                    if (acc[2 * h + mi][r]  > thrv) mask |= 1u << (mi * 4 + r);
                    if (-acc[2 * h + mi][r] > thrv) mask |= 1u << (8 + mi * 4 + r);
                }
            double bvd = -1.0e300; int bid2 = 64;
            while (mask) {
                const int s = __ffs(mask) - 1; mask &= mask - 1;
                const int sign = s >> 3, lr = s & 7, mi = lr >> 2, r = lr & 3;
                const int j   = mi * 16 + 4 * g + r;
                const int idx = sign * 32 + j;
                double a = f64dot_col(qrow, rot, h * 32 + j);
                double v = sign ? -a : a;
                if (v > bvd || (v == bvd && idx < bid2)) { bvd = v; bid2 = idx; }
            }
            #pragma unroll
            for (int off = 16; off < 64; off <<= 1) {
                double ov = __shfl_xor(bvd, off);
                int    oi = __shfl_xor(bid2, off);
                if (ov > bvd || (ov == bvd && oi < bid2)) { bvd = ov; bid2 = oi; }
            }
            bi = bid2;
        }
        if (g == 0) {
            const size_t o = ((size_t)b * HH + h) * SS + tglob;
            bucket_ws[o]  = (unsigned char)bi;
            bucket_out[o] = (float)(bi + h * NBUCK);
        }
    }
}

// ---------------- Kernel B: stable counting sort per (b,h) -------------------
__global__ __launch_bounds__(256) void sort_kernel(
    const unsigned char* __restrict__ bucket_ws, int* __restrict__ st)
{
    __shared__ unsigned int hist[256 * 65];   // padded stride 65
    __shared__ unsigned int totals[64];
    const int tid = threadIdx.x;
    const int bh  = blockIdx.x;               // 0..63 = b*8+h

    unsigned int* hrow = &hist[tid * 65];
    #pragma unroll
    for (int j = 0; j < 65; ++j) hrow[j] = 0u;

    const uint4 raw = *reinterpret_cast<const uint4*>(bucket_ws + (size_t)bh * SS + tid * 16);
    unsigned int w[4] = {raw.x, raw.y, raw.z, raw.w};

    #pragma unroll
    for (int c = 0; c < 16; ++c) {
        unsigned int bk = (w[c >> 2] >> ((c & 3) * 8)) & 255u;
        hrow[bk] += 1u;
    }
    __syncthreads();

    if (tid < 64) {
        unsigned int run = 0;
        for (int c2 = 0; c2 < 256; ++c2) {
            unsigned int x = hist[c2 * 65 + tid];
            hist[c2 * 65 + tid] = run;
            run += x;
        }
        totals[tid] = run;
    }
    __syncthreads();
    if (tid == 0) {
        unsigned int base = 0;
        for (int k = 0; k < 64; ++k) { unsigned int x = totals[k]; totals[k] = base; base += x; }
    }
    __syncthreads();

    int* dst = st + (size_t)bh * SS;
    #pragma unroll
    for (int c = 0; c < 16; ++c) {
        unsigned int bk = (w[c >> 2] >> ((c & 3) * 8)) & 255u;
        unsigned int pos = totals[bk] + hrow[bk];
        hrow[bk] += 1u;
        dst[pos] = tid * 16 + c;
    }
}

// ---------------- Kernel C: chunked attention via bf16 MFMA ------------------
// LDS map (36864 B -> 4 blocks/CU):
//   [0,     34816)  Kb: 128x128 bf16 K tile (QK^T); REUSED as Pb[0,17408) +
//                   Vt[17408,34816) (64-dim half of V^T, two phases)
//   [34816, 35328)  tks[128] int
//   [35328, 35840)  ninv[128] f32
//   [35840, 36864)  psums[256] f32
__global__ __launch_bounds__(256, 4) void attn_kernel(
    const float* __restrict__ qk, const float* __restrict__ vv,
    const int* __restrict__ st, float* __restrict__ logits_ws,
    void* __restrict__ o_ws, const int obf16)
{
    __shared__ __align__(16) char smem[36864];
    char*  Kb    = smem;
    char*  Pb    = smem;                       // after Kb retired
    char*  Vt    = smem + 17408;               // 64 dim-rows x 272 B
    int*   tks   = (int*)(smem + 34816);
    float* ninv  = (float*)(smem + 35328);
    float* psums = (float*)(smem + 35840);

    const int tid = threadIdx.x;
    const int bc  = blockIdx.x;
    const int b   = bc >> 9;
    const int c   = bc & 511;                  // global chunk 0..511
    const int h   = c >> 6;

    if (tid < 128) {
        int src_c = (tid < 64) ? c : ((c == 0) ? (NCHUNK - 1) : (c - 1));
        tks[tid] = st[(size_t)b * HSTOT + (size_t)src_c * CHUNKSZ + (tid & 63)];
    }
    __syncthreads();

    // ---- stage K (raw qk rows, bf16) + sum-of-squares -----------------------
    {
        const int row = tid >> 1, half = tid & 1;
        const int t = tks[row];
        const float* srow = qk + ((size_t)b * SS + t) * DD + half * 64;
        char* krow = Kb + (size_t)row * ROWB + half * 128;
        float ss = 0.f;
        #pragma unroll
        for (int i = 0; i < 8; ++i) {
            float4 v0 = *reinterpret_cast<const float4*>(srow + i * 8);
            float4 v1 = *reinterpret_cast<const float4*>(srow + i * 8 + 4);
            ss = fmaf(v0.x, v0.x, ss); ss = fmaf(v0.y, v0.y, ss);
            ss = fmaf(v0.z, v0.z, ss); ss = fmaf(v0.w, v0.w, ss);
            ss = fmaf(v1.x, v1.x, ss); ss = fmaf(v1.y, v1.y, ss);
            ss = fmaf(v1.z, v1.z, ss); ss = fmaf(v1.w, v1.w, ss);
            uint4 pk;
            pk.x = pk2bf(v0.x, v0.y); pk.y = pk2bf(v0.z, v0.w);
            pk.z = pk2bf(v1.x, v1.y); pk.w = pk2bf(v1.z, v1.w);
            *reinterpret_cast<uint4*>(krow + i * 16) = pk;
        }
        psums[tid] = ss;
    }
    __syncthreads();
    if (tid < 128) ninv[tid] = rsqrtf(psums[2 * tid] + psums[2 * tid + 1] + 1e-6f);
    __syncthreads();

    const int w  = tid >> 6;     // wave id: q-tile rows 16w..16w+15
    const int ln = tid & 63;
    const int cc = ln & 15;      // fragment col lane
    const int g  = ln >> 4;      // fragment k-group / row-group

    // ---- QK^T ---------------------------------------------------------------
    short8_t aq[4];
    #pragma unroll
    for (int ks = 0; ks < 4; ++ks)
        aq[ks] = *reinterpret_cast<const short8_t*>(Kb + (size_t)(16 * w + cc) * ROWB + ks * 64 + g * 16);

    f32x4 acc[8];
    #pragma unroll
    for (int j = 0; j < 8; ++j) {
        acc[j] = (f32x4){0.f, 0.f, 0.f, 0.f};
        #pragma unroll
        for (int ks = 0; ks < 4; ++ks) {
            short8_t bk = *reinterpret_cast<const short8_t*>(Kb + (size_t)(16 * j + cc) * ROWB + ks * 64 + g * 16);
            acc[j] = __builtin_amdgcn_mfma_f32_16x16x32_bf16(aq[ks], bk, acc[j], 0, 0, 0);
        }
    }

    // ---- softmax (regs) -----------------------------------------------------
    const float SCALE = 0.088388347648318447f;   // 128^-0.5
    float lse[4];
    float pr[8][4];
    #pragma unroll
    for (int jr = 0; jr < 4; ++jr) {
        const int q  = 16 * w + 4 * g + jr;
        const int tq = tks[q];
        float m = -3.0e38f;
        #pragma unroll
        for (int j = 0; j < 8; ++j) {
            const int k = 16 * j + cc;
            float val = acc[j][jr] * (ninv[k] * SCALE);
            if (tks[k] == tq) val = -1e5f;
            pr[j][jr] = val;
            m = fmaxf(m, val);
        }
        #pragma unroll
        for (int off = 1; off < 16; off <<= 1) m = fmaxf(m, __shfl_xor(m, off));
        float ssum = 0.f;
        #pragma unroll
        for (int j = 0; j < 8; ++j) { float ex = expf(pr[j][jr] - m); pr[j][jr] = ex; ssum += ex; }
        #pragma unroll
        for (int off = 1; off < 16; off <<= 1) ssum += __shfl_xor(ssum, off);
        const float inv = 1.0f / ssum;
        #pragma unroll
        for (int j = 0; j < 8; ++j) pr[j][jr] *= inv;
        lse[jr] = m + logf(ssum);
    }

    // ---- prefetch V phase 0 (dims 0..63) into regs --------------------------
    const int kp = tid & 63;                // token pair 2kp, 2kp+1
    const int db = tid >> 6;                // dim sub-block (16 dims)
    const int tva = tks[2 * kp], tvb = tks[2 * kp + 1];
    const float* vra = vv + ((size_t)b * SS + tva) * DD + db * 16;
    const float* vrb = vv + ((size_t)b * SS + tvb) * DD + db * 16;
    float4 va[4], vbr[4];
    #pragma unroll
    for (int i = 0; i < 4; ++i) {
        va[i]  = *reinterpret_cast<const float4*>(vra + i * 4);
        vbr[i] = *reinterpret_cast<const float4*>(vrb + i * 4);
    }

    __syncthreads();   // all waves done reading Kb; Pb/Vt may be written

    // ---- write P (bf16) -----------------------------------------------------
    #pragma unroll
    for (int jr = 0; jr < 4; ++jr) {
        const int q = 16 * w + 4 * g + jr;
        #pragma unroll
        for (int j = 0; j < 8; ++j)
            *reinterpret_cast<unsigned short*>(Pb + (size_t)q * ROWB + (16 * j + cc) * 2) = f2bf(pr[j][jr]);
    }
    if (cc == 0) {
        #pragma unroll
        for (int jr = 0; jr < 4; ++jr) {
            const int q = 16 * w + 4 * g + jr;
            logits_ws[((size_t)b * HH + h) * SS + tks[q]] = lse[jr];
        }
    }
    // ---- write V phase 0 to Vt ----------------------------------------------
    {
        const float* fa = reinterpret_cast<const float*>(va);
        const float* fb = reinterpret_cast<const float*>(vbr);
        #pragma unroll
        for (int i = 0; i < 16; ++i) {
            const int dl = db * 16 + i;
            *reinterpret_cast<unsigned int*>(Vt + (size_t)dl * ROWB + kp * 4) = pk2bf(fa[i], fb[i]);
        }
    }
    // ---- prefetch V phase 1 (dims 64..127) into regs (T14 split) ------------
    #pragma unroll
    for (int i = 0; i < 4; ++i) {
        va[i]  = *reinterpret_cast<const float4*>(vra + 64 + i * 4);
        vbr[i] = *reinterpret_cast<const float4*>(vrb + 64 + i * 4);
    }
    __syncthreads();   // Pb + Vt(phase 0) visible

    // ---- PV -----------------------------------------------------------------
    short8_t pa[4];
    #pragma unroll
    for (int ks = 0; ks < 4; ++ks)
        pa[ks] = *reinterpret_cast<const short8_t*>(Pb + (size_t)(16 * w + cc) * ROWB + ks * 64 + g * 16);

    f32x4 oacc[8];
    #pragma unroll
    for (int dt = 0; dt < 4; ++dt) {       // phase A: output dims 0..63
        oacc[dt] = (f32x4){0.f, 0.f, 0.f, 0.f};
        #pragma unroll
        for (int ks = 0; ks < 4; ++ks) {
            short8_t vb = *reinterpret_cast<const short8_t*>(Vt + (size_t)(16 * dt + cc) * ROWB + ks * 64 + g * 16);
            oacc[dt] = __builtin_amdgcn_mfma_f32_16x16x32_bf16(pa[ks], vb, oacc[dt], 0, 0, 0);
        }
    }
    __syncthreads();   // phase-A reads of Vt done

    // ---- write V phase 1 to Vt ----------------------------------------------
    {
        const float* fa = reinterpret_cast<const float*>(va);
        const float* fb = reinterpret_cast<const float*>(vbr);
        #pragma unroll
        for (int i = 0; i < 16; ++i) {
            const int dl = db * 16 + i;
            *reinterpret_cast<unsigned int*>(Vt + (size_t)dl * ROWB + kp * 4) = pk2bf(fa[i], fb[i]);
        }
    }
    __syncthreads();

    #pragma unroll
    for (int dt = 4; dt < 8; ++dt) {       // phase B: output dims 64..127
        oacc[dt] = (f32x4){0.f, 0.f, 0.f, 0.f};
        #pragma unroll
        for (int ks = 0; ks < 4; ++ks) {
            short8_t vb = *reinterpret_cast<const short8_t*>(Vt + (size_t)(16 * (dt - 4) + cc) * ROWB + ks * 64 + g * 16);
            oacc[dt] = __builtin_amdgcn_mfma_f32_16x16x32_bf16(pa[ks], vb, oacc[dt], 0, 0, 0);
        }
    }

    // ---- scatter per-round outputs ------------------------------------------
    #pragma unroll
    for (int jr = 0; jr < 4; ++jr) {
        const int q = 16 * w + 4 * g + jr;
        const int t = tks[q];
        const size_t base = (((size_t)b * HH + h) * SS + t) * DD + cc;
        if (!obf16) {
            float* op = (float*)o_ws;
            #pragma unroll
            for (int dt = 0; dt < 8; ++dt) op[base + 16 * dt] = oacc[dt][jr];
        } else {
            unsigned short* op = (unsigned short*)o_ws;
            #pragma unroll
            for (int dt = 0; dt < 8; ++dt) op[base + 16 * dt] = f2bf(oacc[dt][jr]);
        }
    }
}

// ---------------- Kernel D: softmax-combine over hash rounds -----------------
__global__ __launch_bounds__(256) void combine_kernel(
    const float* __restrict__ logits_ws, const void* __restrict__ o_ws,
    float* __restrict__ outp, const int obf16)
{
    const int gid = blockIdx.x * 256 + threadIdx.x;
    const int row = gid >> 5;     // (b,t)
    const int seg = gid & 31;     // 4-float segment of D
    const int b = row >> 12;
    const int t = row & 4095;

    float l[8];
    float m = -3.0e38f;
    #pragma unroll
    for (int hh = 0; hh < 8; ++hh) {
        l[hh] = logits_ws[((size_t)b * HH + hh) * SS + t];
        m = fmaxf(m, l[hh]);
    }
    float ssum = 0.f;
    #pragma unroll
    for (int hh = 0; hh < 8; ++hh) { l[hh] = expf(l[hh] - m); ssum += l[hh]; }
    const float inv = 1.0f / ssum;

    float a0 = 0.f, a1 = 0.f, a2 = 0.f, a3 = 0.f;
    #pragma unroll
    for (int hh = 0; hh < 8; ++hh) {
        const float wgt = l[hh] * inv;
        const size_t base = (((size_t)b * HH + hh) * SS + t) * DD + seg * 4;
        if (!obf16) {
            float4 ov = *reinterpret_cast<const float4*>((const float*)o_ws + base);
            a0 = fmaf(wgt, ov.x, a0); a1 = fmaf(wgt, ov.y, a1);
            a2 = fmaf(wgt, ov.z, a2); a3 = fmaf(wgt, ov.w, a3);
        } else {
            uint2 u = *reinterpret_cast<const uint2*>((const unsigned short*)o_ws + base);
            a0 = fmaf(wgt, bf2f((unsigned short)(u.x & 0xffffu)), a0);
            a1 = fmaf(wgt, bf2f((unsigned short)(u.x >> 16)), a1);
            a2 = fmaf(wgt, bf2f((unsigned short)(u.y & 0xffffu)), a2);
            a3 = fmaf(wgt, bf2f((unsigned short)(u.y >> 16)), a3);
        }
    }
    *reinterpret_cast<float4*>(outp + ((size_t)b * SS + t) * DD + seg * 4) =
        make_float4(a0, a1, a2, a3);
}

extern "C" void kernel_launch(void* const* d_in, const int* in_sizes, int n_in,
                              void* d_out, int out_size, void* d_ws, size_t ws_size,
                              hipStream_t stream) {
    const float* qk  = (const float*)d_in[0];
    const float* v   = (const float*)d_in[1];
    const float* rot = (const float*)d_in[2];

    float* out        = (float*)d_out;
    float* bucket_out = out + (size_t)BB * SS * DD;   // buckets written as f32

    char* ws = (char*)d_ws;
    int*            st        = (int*)ws;                              // 1,048,576 B
    unsigned char*  bucket_ws = (unsigned char*)(ws + 1048576);        //   262,144 B
    float*          logits_ws = (float*)(ws + 1048576 + 262144);       // 1,048,576 B
    unsigned short* rotT      = (unsigned short*)(ws + 2359296);       //    65,536 B
    void*           o_ws      = (void*)(ws + 2424832);                 // big scratch

    const int obf16 = 1;   // bf16 o-scratch: halves attn WRITE + combine read traffic

    hipLaunchKernelGGL(rot_transpose_kernel, dim3(1), dim3(256), 0, stream, rot, rotT);
    hipLaunchKernelGGL(hash_kernel,    dim3(512),  dim3(256), 0, stream, qk, rot, rotT, bucket_ws, bucket_out);
    hipLaunchKernelGGL(sort_kernel,    dim3(64),   dim3(256), 0, stream, bucket_ws, st);
    hipLaunchKernelGGL(attn_kernel,    dim3(4096), dim3(256), 0, stream, qk, v, st, logits_ws, o_ws, obf16);
    hipLaunchKernelGGL(combine_kernel, dim3(4096), dim3(256), 0, stream, logits_ws, o_ws, out, obf16);
}

// Round 11
// 188.126 us; speedup vs baseline: 1.0558x; 1.0558x over previous
//
#include <hip/hip_runtime.h>
#include <hip/hip_bf16.h>

#define BB 8
#define SS 4096
#define DD 128
#define HH 8
#define NBUCK 64
#define CHUNKSZ 64
#define NCHUNK 512      // HH*SS/CHUNKSZ
#define HSTOT 32768     // HH*SS
#define ROWB 272        // bf16 tile row stride in bytes (128*2 + 16 pad)

typedef __attribute__((ext_vector_type(8))) short short8_t;   // 8 bf16 = 4 VGPR
typedef __attribute__((ext_vector_type(4))) float f32x4;

static __device__ __forceinline__ unsigned short f2bf(float f) {
    __hip_bfloat16 h = __float2bfloat16(f);
    return *reinterpret_cast<unsigned short*>(&h);
}
static __device__ __forceinline__ unsigned int pk2bf(float lo, float hi) {
    __hip_bfloat162 h = __float22bfloat162_rn(make_float2(lo, hi));   // v_cvt_pk_bf16_f32
    return *reinterpret_cast<unsigned int*>(&h);
}
static __device__ __forceinline__ float bf2f(unsigned short u) {
    return __uint_as_float(((unsigned int)u) << 16);
}

// ---------------- Kernel A: LSH hashing (register-resident, h-per-block) -----
// R9 version (measured best). f32 accumulate; near-ties (top-2 gap < TAU=0.01,
// > worst f32 accum err ~1e-3) -> lane-parallel f64 recompute of flagged
// candidates only. MFMA variant (R10) was SLOWER: latency-bound at 2 blocks/CU
// + 3% fallback rate from bf16's wider TAU. Do not re-MFMA this kernel.
__global__ __launch_bounds__(256) void hash_kernel(
    const float* __restrict__ qk, const float* __restrict__ rot,
    unsigned char* __restrict__ bucket_ws, float* __restrict__ bucket_out)
{
    const int tid = threadIdx.x;
    const int bid = blockIdx.x;            // 0..2047 = b(3) | h(3) | tile(5)
    const int b   = bid >> 8;
    const int h   = (bid >> 5) & 7;
    const int t0  = (bid & 31) * 128;
    const int tg  = tid >> 3;              // token group 0..31 (4 tokens each)
    const int jq  = tid & 7;               // j-quad 0..7 (4 columns each)

    const float* qbase = qk + ((size_t)b * SS + t0 + tg * 4) * DD;
    const float* rbase = rot + h * 32 + jq * 4;   // rot[f][h][j], f-stride 256

    float acc[4][4];
    #pragma unroll
    for (int r = 0; r < 4; ++r)
        #pragma unroll
        for (int j = 0; j < 4; ++j) acc[r][j] = 0.f;

    for (int c = 0; c < 16; ++c) {         // f in chunks of 8
        float4 qv[4][2];
        #pragma unroll
        for (int r = 0; r < 4; ++r) {
            qv[r][0] = *reinterpret_cast<const float4*>(qbase + r * DD + c * 8);
            qv[r][1] = *reinterpret_cast<const float4*>(qbase + r * DD + c * 8 + 4);
        }
        float4 rv[8];
        #pragma unroll
        for (int ff = 0; ff < 8; ++ff)
            rv[ff] = *reinterpret_cast<const float4*>(rbase + (size_t)(c * 8 + ff) * (HH * 32));
        #pragma unroll
        for (int ff = 0; ff < 8; ++ff) {
            #pragma unroll
            for (int r = 0; r < 4; ++r) {
                const float4 qh = qv[r][ff >> 2];
                const float qs = (ff & 2) ? ((ff & 1) ? qh.w : qh.z)
                                          : ((ff & 1) ? qh.y : qh.x);
                acc[r][0] = fmaf(qs, rv[ff].x, acc[r][0]);
                acc[r][1] = fmaf(qs, rv[ff].y, acc[r][1]);
                acc[r][2] = fmaf(qs, rv[ff].z, acc[r][2]);
                acc[r][3] = fmaf(qs, rv[ff].w, acc[r][3]);
            }
        }
    }

    const float TAU = 0.01f;
    #pragma unroll
    for (int r = 0; r < 4; ++r) {
        float bv = -3.0e38f; int bi = 0;
        #pragma unroll
        for (int j = 0; j < 4; ++j) {
            float v = acc[r][j];
            if (v > bv) { bv = v; bi = jq * 4 + j; }
        }
        #pragma unroll
        for (int j = 0; j < 4; ++j) {
            float v = -acc[r][j];
            if (v > bv) { bv = v; bi = 32 + jq * 4 + j; }
        }
        #pragma unroll
        for (int off = 1; off < 8; off <<= 1) {
            float ov = __shfl_xor(bv, off);
            int   oi = __shfl_xor(bi, off);
            if (ov > bv || (ov == bv && oi < bi)) { bv = ov; bi = oi; }
        }
        const float thrv = bv - TAU;
        int cnt = 0;
        #pragma unroll
        for (int j = 0; j < 4; ++j) {
            cnt += (acc[r][j]  > thrv) ? 1 : 0;
            cnt += (-acc[r][j] > thrv) ? 1 : 0;
        }
        #pragma unroll
        for (int off = 1; off < 8; off <<= 1) cnt += __shfl_xor(cnt, off);

        const int t = t0 + tg * 4 + r;
        if (cnt > 1) {
            const float* qrow = qk + ((size_t)b * SS + t) * DD;
            double bvd = -1.0e300; int bid2 = 64;
            #pragma unroll
            for (int j = 0; j < 4; ++j) {
                const bool fp = (acc[r][j] > thrv);
                const bool fn = (-acc[r][j] > thrv);
                if (fp || fn) {
                    const float* rcol = rot + h * 32 + jq * 4 + j;
                    double a = 0.0;
                    for (int f = 0; f < DD; ++f)
                        a = fma((double)qrow[f], (double)rcol[(size_t)f * (HH * 32)], a);
                    if (fp &&  a > bvd)                         { bvd = a;  bid2 = jq * 4 + j; }
                    if (fn && (-a > bvd ||
                               (-a == bvd && 32 + jq * 4 + j < bid2))) { bvd = -a; bid2 = 32 + jq * 4 + j; }
                }
            }
            #pragma unroll
            for (int off = 1; off < 8; off <<= 1) {
                double ov = __shfl_xor(bvd, off);
                int    oi = __shfl_xor(bid2, off);
                if (ov > bvd || (ov == bvd && oi < bid2)) { bvd = ov; bid2 = oi; }
            }
            bi = bid2;
        }
        if (jq == 0) {
            const size_t o = ((size_t)b * HH + h) * SS + t;
            bucket_ws[o]  = (unsigned char)bi;
            bucket_out[o] = (float)(bi + h * NBUCK);
        }
    }
}

// ---------------- Kernel B: stable counting sort per (b,h) -------------------
__global__ __launch_bounds__(256) void sort_kernel(
    const unsigned char* __restrict__ bucket_ws, int* __restrict__ st)
{
    __shared__ unsigned int hist[256 * 65];   // padded stride 65
    __shared__ unsigned int totals[64];
    const int tid = threadIdx.x;
    const int bh  = blockIdx.x;               // 0..63 = b*8+h

    unsigned int* hrow = &hist[tid * 65];
    #pragma unroll
    for (int j = 0; j < 65; ++j) hrow[j] = 0u;

    const uint4 raw = *reinterpret_cast<const uint4*>(bucket_ws + (size_t)bh * SS + tid * 16);
    unsigned int w[4] = {raw.x, raw.y, raw.z, raw.w};

    #pragma unroll
    for (int c = 0; c < 16; ++c) {
        unsigned int bk = (w[c >> 2] >> ((c & 3) * 8)) & 255u;
        hrow[bk] += 1u;
    }
    __syncthreads();

    if (tid < 64) {
        unsigned int run = 0;
        for (int c2 = 0; c2 < 256; ++c2) {
            unsigned int x = hist[c2 * 65 + tid];
            hist[c2 * 65 + tid] = run;
            run += x;
        }
        totals[tid] = run;
    }
    __syncthreads();
    if (tid == 0) {
        unsigned int base = 0;
        for (int k = 0; k < 64; ++k) { unsigned int x = totals[k]; totals[k] = base; base += x; }
    }
    __syncthreads();

    int* dst = st + (size_t)bh * SS;
    #pragma unroll
    for (int c = 0; c < 16; ++c) {
        unsigned int bk = (w[c >> 2] >> ((c & 3) * 8)) & 255u;
        unsigned int pos = totals[bk] + hrow[bk];
        hrow[bk] += 1u;
        dst[pos] = tid * 16 + c;
    }
}

// ---------------- Kernel C: chunked attention via bf16 MFMA ------------------
// LDS map (36864 B -> 4 blocks/CU):
//   [0,     34816)  Kb: 128x128 bf16 K tile (QK^T); REUSED as Pb[0,17408) +
//                   Vt[17408,34816) (64-dim half of V^T, two phases)
//   [34816, 35328)  tks[128] int
//   [35328, 35840)  ninv[128] f32
//   [35840, 36864)  psums[256] f32
// R11: K-stage uses a direct per-thread st[] read (no tks barrier on the load
// path; 5 barriers), setprio(1) around MFMA clusters (T5).
__global__ __launch_bounds__(256, 4) void attn_kernel(
    const float* __restrict__ qk, const float* __restrict__ vv,
    const int* __restrict__ st, float* __restrict__ logits_ws,
    void* __restrict__ o_ws, const int obf16)
{
    __shared__ __align__(16) char smem[36864];
    char*  Kb    = smem;
    char*  Pb    = smem;                       // after Kb retired
    char*  Vt    = smem + 17408;               // 64 dim-rows x 272 B
    int*   tks   = (int*)(smem + 34816);
    float* ninv  = (float*)(smem + 35328);
    float* psums = (float*)(smem + 35840);

    const int tid = threadIdx.x;
    const int bc  = blockIdx.x;
    const int b   = bc >> 9;
    const int c   = bc & 511;                  // global chunk 0..511
    const int h   = c >> 6;

    // own K-row index straight from global (L2-hot) -- off the barrier path
    const int rowk  = tid >> 1, halfk = tid & 1;
    const int src_r = (rowk < 64) ? c : ((c == 0) ? (NCHUNK - 1) : (c - 1));
    const int t_mine = st[(size_t)b * HSTOT + (size_t)src_r * CHUNKSZ + (rowk & 63)];

    if (tid < 128) {                           // LDS copy for later phases
        int src_c = (tid < 64) ? c : ((c == 0) ? (NCHUNK - 1) : (c - 1));
        tks[tid] = st[(size_t)b * HSTOT + (size_t)src_c * CHUNKSZ + (tid & 63)];
    }

    // ---- stage K (raw qk rows, bf16) + sum-of-squares (no barrier needed) ---
    {
        const float* srow = qk + ((size_t)b * SS + t_mine) * DD + halfk * 64;
        char* krow = Kb + (size_t)rowk * ROWB + halfk * 128;
        float ss = 0.f;
        #pragma unroll
        for (int i = 0; i < 8; ++i) {
            float4 v0 = *reinterpret_cast<const float4*>(srow + i * 8);
            float4 v1 = *reinterpret_cast<const float4*>(srow + i * 8 + 4);
            ss = fmaf(v0.x, v0.x, ss); ss = fmaf(v0.y, v0.y, ss);
            ss = fmaf(v0.z, v0.z, ss); ss = fmaf(v0.w, v0.w, ss);
            ss = fmaf(v1.x, v1.x, ss); ss = fmaf(v1.y, v1.y, ss);
            ss = fmaf(v1.z, v1.z, ss); ss = fmaf(v1.w, v1.w, ss);
            uint4 pk;
            pk.x = pk2bf(v0.x, v0.y); pk.y = pk2bf(v0.z, v0.w);
            pk.z = pk2bf(v1.x, v1.y); pk.w = pk2bf(v1.z, v1.w);
            *reinterpret_cast<uint4*>(krow + i * 16) = pk;
        }
        psums[tid] = ss;
    }
    __syncthreads();
    if (tid < 128) ninv[tid] = rsqrtf(psums[2 * tid] + psums[2 * tid + 1] + 1e-6f);
    __syncthreads();

    const int w  = tid >> 6;     // wave id: q-tile rows 16w..16w+15
    const int ln = tid & 63;
    const int cc = ln & 15;      // fragment col lane
    const int g  = ln >> 4;      // fragment k-group / row-group

    // ---- QK^T ---------------------------------------------------------------
    short8_t aq[4];
    #pragma unroll
    for (int ks = 0; ks < 4; ++ks)
        aq[ks] = *reinterpret_cast<const short8_t*>(Kb + (size_t)(16 * w + cc) * ROWB + ks * 64 + g * 16);

    f32x4 acc[8];
    __builtin_amdgcn_s_setprio(1);
    #pragma unroll
    for (int j = 0; j < 8; ++j) {
        acc[j] = (f32x4){0.f, 0.f, 0.f, 0.f};
        #pragma unroll
        for (int ks = 0; ks < 4; ++ks) {
            short8_t bk = *reinterpret_cast<const short8_t*>(Kb + (size_t)(16 * j + cc) * ROWB + ks * 64 + g * 16);
            acc[j] = __builtin_amdgcn_mfma_f32_16x16x32_bf16(aq[ks], bk, acc[j], 0, 0, 0);
        }
    }
    __builtin_amdgcn_s_setprio(0);

    // ---- softmax (regs) -----------------------------------------------------
    const float SCALE = 0.088388347648318447f;   // 128^-0.5
    float lse[4];
    float pr[8][4];
    #pragma unroll
    for (int jr = 0; jr < 4; ++jr) {
        const int q  = 16 * w + 4 * g + jr;
        const int tq = tks[q];
        float m = -3.0e38f;
        #pragma unroll
        for (int j = 0; j < 8; ++j) {
            const int k = 16 * j + cc;
            float val = acc[j][jr] * (ninv[k] * SCALE);
            if (tks[k] == tq) val = -1e5f;
            pr[j][jr] = val;
            m = fmaxf(m, val);
        }
        #pragma unroll
        for (int off = 1; off < 16; off <<= 1) m = fmaxf(m, __shfl_xor(m, off));
        float ssum = 0.f;
        #pragma unroll
        for (int j = 0; j < 8; ++j) { float ex = expf(pr[j][jr] - m); pr[j][jr] = ex; ssum += ex; }
        #pragma unroll
        for (int off = 1; off < 16; off <<= 1) ssum += __shfl_xor(ssum, off);
        const float inv = 1.0f / ssum;
        #pragma unroll
        for (int j = 0; j < 8; ++j) pr[j][jr] *= inv;
        lse[jr] = m + logf(ssum);
    }

    // ---- prefetch V phase 0 (dims 0..63) into regs --------------------------
    const int kp = tid & 63;                // token pair 2kp, 2kp+1
    const int db = tid >> 6;                // dim sub-block (16 dims)
    const int tva = tks[2 * kp], tvb = tks[2 * kp + 1];
    const float* vra = vv + ((size_t)b * SS + tva) * DD + db * 16;
    const float* vrb = vv + ((size_t)b * SS + tvb) * DD + db * 16;
    float4 va[4], vbr[4];
    #pragma unroll
    for (int i = 0; i < 4; ++i) {
        va[i]  = *reinterpret_cast<const float4*>(vra + i * 4);
        vbr[i] = *reinterpret_cast<const float4*>(vrb + i * 4);
    }

    __syncthreads();   // all waves done reading Kb; Pb/Vt may be written

    // ---- write P (bf16) -----------------------------------------------------
    #pragma unroll
    for (int jr = 0; jr < 4; ++jr) {
        const int q = 16 * w + 4 * g + jr;
        #pragma unroll
        for (int j = 0; j < 8; ++j)
            *reinterpret_cast<unsigned short*>(Pb + (size_t)q * ROWB + (16 * j + cc) * 2) = f2bf(pr[j][jr]);
    }
    if (cc == 0) {
        #pragma unroll
        for (int jr = 0; jr < 4; ++jr) {
            const int q = 16 * w + 4 * g + jr;
            logits_ws[((size_t)b * HH + h) * SS + tks[q]] = lse[jr];
        }
    }
    // ---- write V phase 0 to Vt ----------------------------------------------
    {
        const float* fa = reinterpret_cast<const float*>(va);
        const float* fb = reinterpret_cast<const float*>(vbr);
        #pragma unroll
        for (int i = 0; i < 16; ++i) {
            const int dl = db * 16 + i;
            *reinterpret_cast<unsigned int*>(Vt + (size_t)dl * ROWB + kp * 4) = pk2bf(fa[i], fb[i]);
        }
    }
    // ---- prefetch V phase 1 (dims 64..127) into regs (T14 split) ------------
    #pragma unroll
    for (int i = 0; i < 4; ++i) {
        va[i]  = *reinterpret_cast<const float4*>(vra + 64 + i * 4);
        vbr[i] = *reinterpret_cast<const float4*>(vrb + 64 + i * 4);
    }
    __syncthreads();   // Pb + Vt(phase 0) visible

    // ---- PV -----------------------------------------------------------------
    short8_t pa[4];
    #pragma unroll
    for (int ks = 0; ks < 4; ++ks)
        pa[ks] = *reinterpret_cast<const short8_t*>(Pb + (size_t)(16 * w + cc) * ROWB + ks * 64 + g * 16);

    f32x4 oacc[8];
    __builtin_amdgcn_s_setprio(1);
    #pragma unroll
    for (int dt = 0; dt < 4; ++dt) {       // phase A: output dims 0..63
        oacc[dt] = (f32x4){0.f, 0.f, 0.f, 0.f};
        #pragma unroll
        for (int ks = 0; ks < 4; ++ks) {
            short8_t vb = *reinterpret_cast<const short8_t*>(Vt + (size_t)(16 * dt + cc) * ROWB + ks * 64 + g * 16);
            oacc[dt] = __builtin_amdgcn_mfma_f32_16x16x32_bf16(pa[ks], vb, oacc[dt], 0, 0, 0);
        }
    }
    __builtin_amdgcn_s_setprio(0);
    __syncthreads();   // phase-A reads of Vt done

    // ---- write V phase 1 to Vt ----------------------------------------------
    {
        const float* fa = reinterpret_cast<const float*>(va);
        const float* fb = reinterpret_cast<const float*>(vbr);
        #pragma unroll
        for (int i = 0; i < 16; ++i) {
            const int dl = db * 16 + i;
            *reinterpret_cast<unsigned int*>(Vt + (size_t)dl * ROWB + kp * 4) = pk2bf(fa[i], fb[i]);
        }
    }
    __syncthreads();

    __builtin_amdgcn_s_setprio(1);
    #pragma unroll
    for (int dt = 4; dt < 8; ++dt) {       // phase B: output dims 64..127
        oacc[dt] = (f32x4){0.f, 0.f, 0.f, 0.f};
        #pragma unroll
        for (int ks = 0; ks < 4; ++ks) {
            short8_t vb = *reinterpret_cast<const short8_t*>(Vt + (size_t)(16 * (dt - 4) + cc) * ROWB + ks * 64 + g * 16);
            oacc[dt] = __builtin_amdgcn_mfma_f32_16x16x32_bf16(pa[ks], vb, oacc[dt], 0, 0, 0);
        }
    }
    __builtin_amdgcn_s_setprio(0);

    // ---- scatter per-round outputs ------------------------------------------
    #pragma unroll
    for (int jr = 0; jr < 4; ++jr) {
        const int q = 16 * w + 4 * g + jr;
        const int t = tks[q];
        const size_t base = (((size_t)b * HH + h) * SS + t) * DD + cc;
        if (!obf16) {
            float* op = (float*)o_ws;
            #pragma unroll
            for (int dt = 0; dt < 8; ++dt) op[base + 16 * dt] = oacc[dt][jr];
        } else {
            unsigned short* op = (unsigned short*)o_ws;
            #pragma unroll
            for (int dt = 0; dt < 8; ++dt) op[base + 16 * dt] = f2bf(oacc[dt][jr]);
        }
    }
}

// ---------------- Kernel D: softmax-combine over hash rounds -----------------
__global__ __launch_bounds__(256) void combine_kernel(
    const float* __restrict__ logits_ws, const void* __restrict__ o_ws,
    float* __restrict__ outp, const int obf16)
{
    const int gid = blockIdx.x * 256 + threadIdx.x;
    const int row = gid >> 5;     // (b,t)
    const int seg = gid & 31;     // 4-float segment of D
    const int b = row >> 12;
    const int t = row & 4095;

    float l[8];
    float m = -3.0e38f;
    #pragma unroll
    for (int hh = 0; hh < 8; ++hh) {
        l[hh] = logits_ws[((size_t)b * HH + hh) * SS + t];
        m = fmaxf(m, l[hh]);
    }
    float ssum = 0.f;
    #pragma unroll
    for (int hh = 0; hh < 8; ++hh) { l[hh] = expf(l[hh] - m); ssum += l[hh]; }
    const float inv = 1.0f / ssum;

    float a0 = 0.f, a1 = 0.f, a2 = 0.f, a3 = 0.f;
    #pragma unroll
    for (int hh = 0; hh < 8; ++hh) {
        const float wgt = l[hh] * inv;
        const size_t base = (((size_t)b * HH + hh) * SS + t) * DD + seg * 4;
        if (!obf16) {
            float4 ov = *reinterpret_cast<const float4*>((const float*)o_ws + base);
            a0 = fmaf(wgt, ov.x, a0); a1 = fmaf(wgt, ov.y, a1);
            a2 = fmaf(wgt, ov.z, a2); a3 = fmaf(wgt, ov.w, a3);
        } else {
            uint2 u = *reinterpret_cast<const uint2*>((const unsigned short*)o_ws + base);
            a0 = fmaf(wgt, bf2f((unsigned short)(u.x & 0xffffu)), a0);
            a1 = fmaf(wgt, bf2f((unsigned short)(u.x >> 16)), a1);
            a2 = fmaf(wgt, bf2f((unsigned short)(u.y & 0xffffu)), a2);
            a3 = fmaf(wgt, bf2f((unsigned short)(u.y >> 16)), a3);
        }
    }
    *reinterpret_cast<float4*>(outp + ((size_t)b * SS + t) * DD + seg * 4) =
        make_float4(a0, a1, a2, a3);
}

extern "C" void kernel_launch(void* const* d_in, const int* in_sizes, int n_in,
                              void* d_out, int out_size, void* d_ws, size_t ws_size,
                              hipStream_t stream) {
    const float* qk  = (const float*)d_in[0];
    const float* v   = (const float*)d_in[1];
    const float* rot = (const float*)d_in[2];

    float* out        = (float*)d_out;
    float* bucket_out = out + (size_t)BB * SS * DD;   // buckets written as f32

    char* ws = (char*)d_ws;
    int*            st        = (int*)ws;                              // 1,048,576 B
    unsigned char*  bucket_ws = (unsigned char*)(ws + 1048576);        //   262,144 B
    float*          logits_ws = (float*)(ws + 1048576 + 262144);       // 1,048,576 B
    void*           o_ws      = (void*)(ws + 2359296);                 // big scratch

    const int obf16 = 1;   // bf16 o-scratch: halves attn WRITE + combine read traffic

    hipLaunchKernelGGL(hash_kernel,    dim3(2048), dim3(256), 0, stream, qk, rot, bucket_ws, bucket_out);
    hipLaunchKernelGGL(sort_kernel,    dim3(64),   dim3(256), 0, stream, bucket_ws, st);
    hipLaunchKernelGGL(attn_kernel,    dim3(4096), dim3(256), 0, stream, qk, v, st, logits_ws, o_ws, obf16);
    hipLaunchKernelGGL(combine_kernel, dim3(4096), dim3(256), 0, stream, logits_ws, o_ws, out, obf16);
}

// Round 12
// 179.411 us; speedup vs baseline: 1.1071x; 1.0486x over previous
//
#include <hip/hip_runtime.h>
#include <hip/hip_bf16.h>

#define BB 8
#define SS 4096
#define DD 128
#define HH 8
#define NBUCK 64
#define CHUNKSZ 64
#define NCHUNK 512      // HH*SS/CHUNKSZ
#define HSTOT 32768     // HH*SS
#define ROWB 272        // bf16 tile row stride in bytes (128*2 + 16 pad)

typedef __attribute__((ext_vector_type(8))) short short8_t;   // 8 bf16 = 4 VGPR
typedef __attribute__((ext_vector_type(4))) float f32x4;

static __device__ __forceinline__ unsigned short f2bf(float f) {
    __hip_bfloat16 h = __float2bfloat16(f);
    return *reinterpret_cast<unsigned short*>(&h);
}
static __device__ __forceinline__ unsigned int pk2bf(float lo, float hi) {
    __hip_bfloat162 h = __float22bfloat162_rn(make_float2(lo, hi));   // v_cvt_pk_bf16_f32
    return *reinterpret_cast<unsigned int*>(&h);
}
static __device__ __forceinline__ float bf2f(unsigned short u) {
    return __uint_as_float(((unsigned int)u) << 16);
}

// ---------------- Kernel A: LSH hashing (register-resident) ------------------
// R9 structure (measured best; R10 MFMA variant was slower -- latency-bound).
// R12: batch pinned to XCD via low-3-bits block id (XCD = dispatch % 8) so
// qk[b] (2MB) stays L2-resident across that batch's 8 h-rounds x 32 tiles.
__global__ __launch_bounds__(256) void hash_kernel(
    const float* __restrict__ qk, const float* __restrict__ rot,
    unsigned char* __restrict__ bucket_ws, float* __restrict__ bucket_out)
{
    const int tid = threadIdx.x;
    const int bid = blockIdx.x;            // 0..2047 = tile(5) | h(3) | b(3)
    const int b   = bid & 7;               // XCD-pinned batch
    const int h   = (bid >> 3) & 7;
    const int t0  = (bid >> 6) * 128;
    const int tg  = tid >> 3;              // token group 0..31 (4 tokens each)
    const int jq  = tid & 7;               // j-quad 0..7 (4 columns each)

    const float* qbase = qk + ((size_t)b * SS + t0 + tg * 4) * DD;
    const float* rbase = rot + h * 32 + jq * 4;   // rot[f][h][j], f-stride 256

    float acc[4][4];
    #pragma unroll
    for (int r = 0; r < 4; ++r)
        #pragma unroll
        for (int j = 0; j < 4; ++j) acc[r][j] = 0.f;

    for (int c = 0; c < 16; ++c) {         // f in chunks of 8
        float4 qv[4][2];
        #pragma unroll
        for (int r = 0; r < 4; ++r) {
            qv[r][0] = *reinterpret_cast<const float4*>(qbase + r * DD + c * 8);
            qv[r][1] = *reinterpret_cast<const float4*>(qbase + r * DD + c * 8 + 4);
        }
        float4 rv[8];
        #pragma unroll
        for (int ff = 0; ff < 8; ++ff)
            rv[ff] = *reinterpret_cast<const float4*>(rbase + (size_t)(c * 8 + ff) * (HH * 32));
        #pragma unroll
        for (int ff = 0; ff < 8; ++ff) {
            #pragma unroll
            for (int r = 0; r < 4; ++r) {
                const float4 qh = qv[r][ff >> 2];
                const float qs = (ff & 2) ? ((ff & 1) ? qh.w : qh.z)
                                          : ((ff & 1) ? qh.y : qh.x);
                acc[r][0] = fmaf(qs, rv[ff].x, acc[r][0]);
                acc[r][1] = fmaf(qs, rv[ff].y, acc[r][1]);
                acc[r][2] = fmaf(qs, rv[ff].z, acc[r][2]);
                acc[r][3] = fmaf(qs, rv[ff].w, acc[r][3]);
            }
        }
    }

    const float TAU = 0.01f;
    #pragma unroll
    for (int r = 0; r < 4; ++r) {
        float bv = -3.0e38f; int bi = 0;
        #pragma unroll
        for (int j = 0; j < 4; ++j) {
            float v = acc[r][j];
            if (v > bv) { bv = v; bi = jq * 4 + j; }
        }
        #pragma unroll
        for (int j = 0; j < 4; ++j) {
            float v = -acc[r][j];
            if (v > bv) { bv = v; bi = 32 + jq * 4 + j; }
        }
        #pragma unroll
        for (int off = 1; off < 8; off <<= 1) {
            float ov = __shfl_xor(bv, off);
            int   oi = __shfl_xor(bi, off);
            if (ov > bv || (ov == bv && oi < bi)) { bv = ov; bi = oi; }
        }
        const float thrv = bv - TAU;
        int cnt = 0;
        #pragma unroll
        for (int j = 0; j < 4; ++j) {
            cnt += (acc[r][j]  > thrv) ? 1 : 0;
            cnt += (-acc[r][j] > thrv) ? 1 : 0;
        }
        #pragma unroll
        for (int off = 1; off < 8; off <<= 1) cnt += __shfl_xor(cnt, off);

        const int t = t0 + tg * 4 + r;
        if (cnt > 1) {
            const float* qrow = qk + ((size_t)b * SS + t) * DD;
            double bvd = -1.0e300; int bid2 = 64;
            #pragma unroll
            for (int j = 0; j < 4; ++j) {
                const bool fp = (acc[r][j] > thrv);
                const bool fn = (-acc[r][j] > thrv);
                if (fp || fn) {
                    const float* rcol = rot + h * 32 + jq * 4 + j;
                    double a = 0.0;
                    for (int f = 0; f < DD; ++f)
                        a = fma((double)qrow[f], (double)rcol[(size_t)f * (HH * 32)], a);
                    if (fp &&  a > bvd)                         { bvd = a;  bid2 = jq * 4 + j; }
                    if (fn && (-a > bvd ||
                               (-a == bvd && 32 + jq * 4 + j < bid2))) { bvd = -a; bid2 = 32 + jq * 4 + j; }
                }
            }
            #pragma unroll
            for (int off = 1; off < 8; off <<= 1) {
                double ov = __shfl_xor(bvd, off);
                int    oi = __shfl_xor(bid2, off);
                if (ov > bvd || (ov == bvd && oi < bid2)) { bvd = ov; bid2 = oi; }
            }
            bi = bid2;
        }
        if (jq == 0) {
            const size_t o = ((size_t)b * HH + h) * SS + t;
            bucket_ws[o]  = (unsigned char)bi;
            bucket_out[o] = (float)(bi + h * NBUCK);
        }
    }
}

// ---------------- Kernel B: stable counting sort per (b,h) -------------------
__global__ __launch_bounds__(256) void sort_kernel(
    const unsigned char* __restrict__ bucket_ws, int* __restrict__ st)
{
    __shared__ unsigned int hist[256 * 65];   // padded stride 65
    __shared__ unsigned int totals[64];
    const int tid = threadIdx.x;
    const int bh  = blockIdx.x;               // 0..63 = b*8+h

    unsigned int* hrow = &hist[tid * 65];
    #pragma unroll
    for (int j = 0; j < 65; ++j) hrow[j] = 0u;

    const uint4 raw = *reinterpret_cast<const uint4*>(bucket_ws + (size_t)bh * SS + tid * 16);
    unsigned int w[4] = {raw.x, raw.y, raw.z, raw.w};

    #pragma unroll
    for (int c = 0; c < 16; ++c) {
        unsigned int bk = (w[c >> 2] >> ((c & 3) * 8)) & 255u;
        hrow[bk] += 1u;
    }
    __syncthreads();

    if (tid < 64) {
        unsigned int run = 0;
        for (int c2 = 0; c2 < 256; ++c2) {
            unsigned int x = hist[c2 * 65 + tid];
            hist[c2 * 65 + tid] = run;
            run += x;
        }
        totals[tid] = run;
    }
    __syncthreads();
    if (tid == 0) {
        unsigned int base = 0;
        for (int k = 0; k < 64; ++k) { unsigned int x = totals[k]; totals[k] = base; base += x; }
    }
    __syncthreads();

    int* dst = st + (size_t)bh * SS;
    #pragma unroll
    for (int c = 0; c < 16; ++c) {
        unsigned int bk = (w[c >> 2] >> ((c & 3) * 8)) & 255u;
        unsigned int pos = totals[bk] + hrow[bk];
        hrow[bk] += 1u;
        dst[pos] = tid * 16 + c;
    }
}

// ---------------- Kernel C: chunked attention via bf16 MFMA ------------------
// LDS map (36864 B -> 4 blocks/CU):
//   [0,     34816)  Kb: 128x128 bf16 K tile (QK^T); REUSED as Pb[0,17408) +
//                   Vt[17408,34816) (64-dim half of V^T, two phases)
//   [34816, 35328)  tks[128] int
//   [35328, 35840)  ninv[128] f32
//   [35840, 36864)  psums[256] f32
// R12: batch pinned to XCD (b = bc & 7): the per-(b,h) sorted-token gathers of
// qk[b]+v[b] (4MB) hit a single XCD's 4MB L2 instead of thrashing all eight.
__global__ __launch_bounds__(256, 4) void attn_kernel(
    const float* __restrict__ qk, const float* __restrict__ vv,
    const int* __restrict__ st, float* __restrict__ logits_ws,
    void* __restrict__ o_ws, const int obf16)
{
    __shared__ __align__(16) char smem[36864];
    char*  Kb    = smem;
    char*  Pb    = smem;                       // after Kb retired
    char*  Vt    = smem + 17408;               // 64 dim-rows x 272 B
    int*   tks   = (int*)(smem + 34816);
    float* ninv  = (float*)(smem + 35328);
    float* psums = (float*)(smem + 35840);

    const int tid = threadIdx.x;
    const int bc  = blockIdx.x;
    const int b   = bc & 7;                    // XCD-pinned batch
    const int c   = bc >> 3;                   // chunk 0..511
    const int h   = c >> 6;

    // own K-row index straight from global (L2-hot) -- off the barrier path
    const int rowk  = tid >> 1, halfk = tid & 1;
    const int src_r = (rowk < 64) ? c : ((c == 0) ? (NCHUNK - 1) : (c - 1));
    const int t_mine = st[(size_t)b * HSTOT + (size_t)src_r * CHUNKSZ + (rowk & 63)];

    if (tid < 128) {                           // LDS copy for later phases
        int src_c = (tid < 64) ? c : ((c == 0) ? (NCHUNK - 1) : (c - 1));
        tks[tid] = st[(size_t)b * HSTOT + (size_t)src_c * CHUNKSZ + (tid & 63)];
    }

    // ---- stage K (raw qk rows, bf16) + sum-of-squares (no barrier needed) ---
    {
        const float* srow = qk + ((size_t)b * SS + t_mine) * DD + halfk * 64;
        char* krow = Kb + (size_t)rowk * ROWB + halfk * 128;
        float ss = 0.f;
        #pragma unroll
        for (int i = 0; i < 8; ++i) {
            float4 v0 = *reinterpret_cast<const float4*>(srow + i * 8);
            float4 v1 = *reinterpret_cast<const float4*>(srow + i * 8 + 4);
            ss = fmaf(v0.x, v0.x, ss); ss = fmaf(v0.y, v0.y, ss);
            ss = fmaf(v0.z, v0.z, ss); ss = fmaf(v0.w, v0.w, ss);
            ss = fmaf(v1.x, v1.x, ss); ss = fmaf(v1.y, v1.y, ss);
            ss = fmaf(v1.z, v1.z, ss); ss = fmaf(v1.w, v1.w, ss);
            uint4 pk;
            pk.x = pk2bf(v0.x, v0.y); pk.y = pk2bf(v0.z, v0.w);
            pk.z = pk2bf(v1.x, v1.y); pk.w = pk2bf(v1.z, v1.w);
            *reinterpret_cast<uint4*>(krow + i * 16) = pk;
        }
        psums[tid] = ss;
    }
    __syncthreads();
    if (tid < 128) ninv[tid] = rsqrtf(psums[2 * tid] + psums[2 * tid + 1] + 1e-6f);
    __syncthreads();

    const int w  = tid >> 6;     // wave id: q-tile rows 16w..16w+15
    const int ln = tid & 63;
    const int cc = ln & 15;      // fragment col lane
    const int g  = ln >> 4;      // fragment k-group / row-group

    // ---- QK^T ---------------------------------------------------------------
    short8_t aq[4];
    #pragma unroll
    for (int ks = 0; ks < 4; ++ks)
        aq[ks] = *reinterpret_cast<const short8_t*>(Kb + (size_t)(16 * w + cc) * ROWB + ks * 64 + g * 16);

    f32x4 acc[8];
    __builtin_amdgcn_s_setprio(1);
    #pragma unroll
    for (int j = 0; j < 8; ++j) {
        acc[j] = (f32x4){0.f, 0.f, 0.f, 0.f};
        #pragma unroll
        for (int ks = 0; ks < 4; ++ks) {
            short8_t bk = *reinterpret_cast<const short8_t*>(Kb + (size_t)(16 * j + cc) * ROWB + ks * 64 + g * 16);
            acc[j] = __builtin_amdgcn_mfma_f32_16x16x32_bf16(aq[ks], bk, acc[j], 0, 0, 0);
        }
    }
    __builtin_amdgcn_s_setprio(0);

    // ---- softmax (regs) -----------------------------------------------------
    const float SCALE = 0.088388347648318447f;   // 128^-0.5
    float lse[4];
    float pr[8][4];
    #pragma unroll
    for (int jr = 0; jr < 4; ++jr) {
        const int q  = 16 * w + 4 * g + jr;
        const int tq = tks[q];
        float m = -3.0e38f;
        #pragma unroll
        for (int j = 0; j < 8; ++j) {
            const int k = 16 * j + cc;
            float val = acc[j][jr] * (ninv[k] * SCALE);
            if (tks[k] == tq) val = -1e5f;
            pr[j][jr] = val;
            m = fmaxf(m, val);
        }
        #pragma unroll
        for (int off = 1; off < 16; off <<= 1) m = fmaxf(m, __shfl_xor(m, off));
        float ssum = 0.f;
        #pragma unroll
        for (int j = 0; j < 8; ++j) { float ex = expf(pr[j][jr] - m); pr[j][jr] = ex; ssum += ex; }
        #pragma unroll
        for (int off = 1; off < 16; off <<= 1) ssum += __shfl_xor(ssum, off);
        const float inv = 1.0f / ssum;
        #pragma unroll
        for (int j = 0; j < 8; ++j) pr[j][jr] *= inv;
        lse[jr] = m + logf(ssum);
    }

    // ---- prefetch V phase 0 (dims 0..63) into regs --------------------------
    const int kp = tid & 63;                // token pair 2kp, 2kp+1
    const int db = tid >> 6;                // dim sub-block (16 dims)
    const int tva = tks[2 * kp], tvb = tks[2 * kp + 1];
    const float* vra = vv + ((size_t)b * SS + tva) * DD + db * 16;
    const float* vrb = vv + ((size_t)b * SS + tvb) * DD + db * 16;
    float4 va[4], vbr[4];
    #pragma unroll
    for (int i = 0; i < 4; ++i) {
        va[i]  = *reinterpret_cast<const float4*>(vra + i * 4);
        vbr[i] = *reinterpret_cast<const float4*>(vrb + i * 4);
    }

    __syncthreads();   // all waves done reading Kb; Pb/Vt may be written

    // ---- write P (bf16) -----------------------------------------------------
    #pragma unroll
    for (int jr = 0; jr < 4; ++jr) {
        const int q = 16 * w + 4 * g + jr;
        #pragma unroll
        for (int j = 0; j < 8; ++j)
            *reinterpret_cast<unsigned short*>(Pb + (size_t)q * ROWB + (16 * j + cc) * 2) = f2bf(pr[j][jr]);
    }
    if (cc == 0) {
        #pragma unroll
        for (int jr = 0; jr < 4; ++jr) {
            const int q = 16 * w + 4 * g + jr;
            logits_ws[((size_t)b * HH + h) * SS + tks[q]] = lse[jr];
        }
    }
    // ---- write V phase 0 to Vt ----------------------------------------------
    {
        const float* fa = reinterpret_cast<const float*>(va);
        const float* fb = reinterpret_cast<const float*>(vbr);
        #pragma unroll
        for (int i = 0; i < 16; ++i) {
            const int dl = db * 16 + i;
            *reinterpret_cast<unsigned int*>(Vt + (size_t)dl * ROWB + kp * 4) = pk2bf(fa[i], fb[i]);
        }
    }
    // ---- prefetch V phase 1 (dims 64..127) into regs (T14 split) ------------
    #pragma unroll
    for (int i = 0; i < 4; ++i) {
        va[i]  = *reinterpret_cast<const float4*>(vra + 64 + i * 4);
        vbr[i] = *reinterpret_cast<const float4*>(vrb + 64 + i * 4);
    }
    __syncthreads();   // Pb + Vt(phase 0) visible

    // ---- PV -----------------------------------------------------------------
    short8_t pa[4];
    #pragma unroll
    for (int ks = 0; ks < 4; ++ks)
        pa[ks] = *reinterpret_cast<const short8_t*>(Pb + (size_t)(16 * w + cc) * ROWB + ks * 64 + g * 16);

    f32x4 oacc[8];
    __builtin_amdgcn_s_setprio(1);
    #pragma unroll
    for (int dt = 0; dt < 4; ++dt) {       // phase A: output dims 0..63
        oacc[dt] = (f32x4){0.f, 0.f, 0.f, 0.f};
        #pragma unroll
        for (int ks = 0; ks < 4; ++ks) {
            short8_t vb = *reinterpret_cast<const short8_t*>(Vt + (size_t)(16 * dt + cc) * ROWB + ks * 64 + g * 16);
            oacc[dt] = __builtin_amdgcn_mfma_f32_16x16x32_bf16(pa[ks], vb, oacc[dt], 0, 0, 0);
        }
    }
    __builtin_amdgcn_s_setprio(0);
    __syncthreads();   // phase-A reads of Vt done

    // ---- write V phase 1 to Vt ----------------------------------------------
    {
        const float* fa = reinterpret_cast<const float*>(va);
        const float* fb = reinterpret_cast<const float*>(vbr);
        #pragma unroll
        for (int i = 0; i < 16; ++i) {
            const int dl = db * 16 + i;
            *reinterpret_cast<unsigned int*>(Vt + (size_t)dl * ROWB + kp * 4) = pk2bf(fa[i], fb[i]);
        }
    }
    __syncthreads();

    __builtin_amdgcn_s_setprio(1);
    #pragma unroll
    for (int dt = 4; dt < 8; ++dt) {       // phase B: output dims 64..127
        oacc[dt] = (f32x4){0.f, 0.f, 0.f, 0.f};
        #pragma unroll
        for (int ks = 0; ks < 4; ++ks) {
            short8_t vb = *reinterpret_cast<const short8_t*>(Vt + (size_t)(16 * (dt - 4) + cc) * ROWB + ks * 64 + g * 16);
            oacc[dt] = __builtin_amdgcn_mfma_f32_16x16x32_bf16(pa[ks], vb, oacc[dt], 0, 0, 0);
        }
    }
    __builtin_amdgcn_s_setprio(0);

    // ---- scatter per-round outputs ------------------------------------------
    #pragma unroll
    for (int jr = 0; jr < 4; ++jr) {
        const int q = 16 * w + 4 * g + jr;
        const int t = tks[q];
        const size_t base = (((size_t)b * HH + h) * SS + t) * DD + cc;
        if (!obf16) {
            float* op = (float*)o_ws;
            #pragma unroll
            for (int dt = 0; dt < 8; ++dt) op[base + 16 * dt] = oacc[dt][jr];
        } else {
            unsigned short* op = (unsigned short*)o_ws;
            #pragma unroll
            for (int dt = 0; dt < 8; ++dt) op[base + 16 * dt] = f2bf(oacc[dt][jr]);
        }
    }
}

// ---------------- Kernel D: softmax-combine over hash rounds -----------------
__global__ __launch_bounds__(256) void combine_kernel(
    const float* __restrict__ logits_ws, const void* __restrict__ o_ws,
    float* __restrict__ outp, const int obf16)
{
    const int gid = blockIdx.x * 256 + threadIdx.x;
    const int row = gid >> 5;     // (b,t)
    const int seg = gid & 31;     // 4-float segment of D
    const int b = row >> 12;
    const int t = row & 4095;

    float l[8];
    float m = -3.0e38f;
    #pragma unroll
    for (int hh = 0; hh < 8; ++hh) {
        l[hh] = logits_ws[((size_t)b * HH + hh) * SS + t];
        m = fmaxf(m, l[hh]);
    }
    float ssum = 0.f;
    #pragma unroll
    for (int hh = 0; hh < 8; ++hh) { l[hh] = expf(l[hh] - m); ssum += l[hh]; }
    const float inv = 1.0f / ssum;

    float a0 = 0.f, a1 = 0.f, a2 = 0.f, a3 = 0.f;
    #pragma unroll
    for (int hh = 0; hh < 8; ++hh) {
        const float wgt = l[hh] * inv;
        const size_t base = (((size_t)b * HH + hh) * SS + t) * DD + seg * 4;
        if (!obf16) {
            float4 ov = *reinterpret_cast<const float4*>((const float*)o_ws + base);
            a0 = fmaf(wgt, ov.x, a0); a1 = fmaf(wgt, ov.y, a1);
            a2 = fmaf(wgt, ov.z, a2); a3 = fmaf(wgt, ov.w, a3);
        } else {
            uint2 u = *reinterpret_cast<const uint2*>((const unsigned short*)o_ws + base);
            a0 = fmaf(wgt, bf2f((unsigned short)(u.x & 0xffffu)), a0);
            a1 = fmaf(wgt, bf2f((unsigned short)(u.x >> 16)), a1);
            a2 = fmaf(wgt, bf2f((unsigned short)(u.y & 0xffffu)), a2);
            a3 = fmaf(wgt, bf2f((unsigned short)(u.y >> 16)), a3);
        }
    }
    *reinterpret_cast<float4*>(outp + ((size_t)b * SS + t) * DD + seg * 4) =
        make_float4(a0, a1, a2, a3);
}

extern "C" void kernel_launch(void* const* d_in, const int* in_sizes, int n_in,
                              void* d_out, int out_size, void* d_ws, size_t ws_size,
                              hipStream_t stream) {
    const float* qk  = (const float*)d_in[0];
    const float* v   = (const float*)d_in[1];
    const float* rot = (const float*)d_in[2];

    float* out        = (float*)d_out;
    float* bucket_out = out + (size_t)BB * SS * DD;   // buckets written as f32

    char* ws = (char*)d_ws;
    int*            st        = (int*)ws;                              // 1,048,576 B
    unsigned char*  bucket_ws = (unsigned char*)(ws + 1048576);        //   262,144 B
    float*          logits_ws = (float*)(ws + 1048576 + 262144);       // 1,048,576 B
    void*           o_ws      = (void*)(ws + 2359296);                 // big scratch

    const int obf16 = 1;   // bf16 o-scratch: halves attn WRITE + combine read traffic

    hipLaunchKernelGGL(hash_kernel,    dim3(2048), dim3(256), 0, stream, qk, rot, bucket_ws, bucket_out);
    hipLaunchKernelGGL(sort_kernel,    dim3(64),   dim3(256), 0, stream, bucket_ws, st);
    hipLaunchKernelGGL(attn_kernel,    dim3(4096), dim3(256), 0, stream, qk, v, st, logits_ws, o_ws, obf16);
    hipLaunchKernelGGL(combine_kernel, dim3(4096), dim3(256), 0, stream, logits_ws, o_ws, out, obf16);
}